// Round 11
// baseline (117.200 us; speedup 1.0000x reference)
//
#include <hip/hip_runtime.h>

// GuidedCnn: fused offset-conv (8ch -> 18ch, 3x3) + deformable conv.
// R11: sampling tile stored as 3x bf16 packed in 8 B/pixel -> every bilinear
// corner is one aligned ds_read_b64 (+3 shift/mask unpacks). R9b's 12 B/px
// stride broke b128 merging (unprovable alignment -> scalar b32 reads).
// LDS 24.1 KB -> 6 blocks/CU. Keeps: pk-fma lerp epilogue, bias in MFMA C,
// B-frags precomputed in d_ws, K=96 tap-major MFMA GEMM.

#define Bn 8
#define Hn 384
#define Wn 384
#define HWn (Hn * Wn)
#define TILE 16
#define PH 4
#define PT 24                  // pf sampling tile extent (halo 4)

// LDS float-offset map
#define OFF_PTILE 0
#define SZ_PTILE (PT * PT * 2)           // 1152 "floats" = 8 B/px bf16x3
#define OFF_T8   SZ_PTILE
#define SZ_T8U   4864                    // max(t8b 324*4=1296, offb 256*19=4864)
#define SMEM_FLOATS (OFF_T8 + SZ_T8U)    // 6016 floats = 24,064 B

typedef float f32x4 __attribute__((ext_vector_type(4)));
typedef float f32x2 __attribute__((ext_vector_type(2)));
typedef unsigned u32x2 __attribute__((ext_vector_type(2)));
typedef short s16x8 __attribute__((ext_vector_type(8)));

static __device__ inline f32x2 vfma2(f32x2 a, f32x2 b, f32x2 c) {
#if __has_builtin(__builtin_elementwise_fma)
    return __builtin_elementwise_fma(a, b, c);
#else
    f32x2 r; r.x = fmaf(a.x, b.x, c.x); r.y = fmaf(a.y, b.y, c.y); return r;
#endif
}
static __device__ inline f32x2 vfloor2(f32x2 a) {
#if __has_builtin(__builtin_elementwise_floor)
    return __builtin_elementwise_floor(a);
#else
    f32x2 r; r.x = floorf(a.x); r.y = floorf(a.y); return r;
#endif
}
static __device__ inline f32x2 splat2(float s) {
    f32x2 r; r.x = s; r.y = s; return r;
}

__device__ inline unsigned short rne_bf16(float f) {
    unsigned u = __float_as_uint(f);
    u += 0x7fffu + ((u >> 16) & 1u);
    return (unsigned short)(u >> 16);
}

// ---- prep: B-fragments, layout [sg = s*2+nt][lane][j=ch], k = tap*8+ch ----
__global__ void prep_bw(const float* __restrict__ ow, unsigned short* __restrict__ bwg) {
    const int idx = blockIdx.x * 64 + threadIdx.x;   // 0..383
    const int sg   = idx >> 6;
    const int lane = idx & 63;
    const int s  = sg >> 1;
    const int nt = sg & 1;
    const int am = lane & 15;
    const int g  = lane >> 4;
    const int oc = nt * 16 + am;
    const int t  = 4 * s + g;                        // tap 0..11
    union { unsigned short h[8]; s16x8 v; } F;
#pragma unroll
    for (int c = 0; c < 8; ++c) {
        float w = 0.f;
        if (t < 9 && oc < 18) w = ow[oc * 72 + c * 9 + t];
        F.h[c] = rne_bf16(w);
    }
    ((s16x8*)bwg)[idx] = F.v;
}

__global__ __launch_bounds__(256, 6) void guided_cnn_fused(
    const float* __restrict__ pf, const float* __restrict__ cf,
    const float* __restrict__ mv, const s16x8* __restrict__ bwg,
    const float* __restrict__ ob, const float* __restrict__ dw,
    float* __restrict__ out)
{
    __shared__ float smem[SMEM_FLOATS];

    const int tid = threadIdx.x;
    const int b = blockIdx.z;
    const int tileY0 = blockIdx.y * TILE;
    const int tileX0 = blockIdx.x * TILE;
    const int oy = tileY0 - PH;
    const int ox = tileX0 - PH;

    unsigned* ptileB = (unsigned*)(smem + OFF_PTILE); // [pix]{c0|c1<<16, c2}
    float* t8b = smem + OFF_T8;          // bf16 conv tile: [pix][8ch] = 16B

    const int lane = tid & 63;
    const int wv   = tid >> 6;
    const int am   = lane & 15;
    const int g    = lane >> 4;

    // ---- B-fragments: 6 coalesced b128 loads from precomputed d_ws ----
    s16x8 bfrag[3][2];
#pragma unroll
    for (int s = 0; s < 3; ++s)
#pragma unroll
        for (int nt = 0; nt < 2; ++nt)
            bfrag[s][nt] = bwg[(s * 2 + nt) * 64 + lane];

    // bias for this lane's D-columns (C-operand init)
    const float bias0 = ob[am];
    const float bias1 = ob[am < 2 ? 16 + am : 17];   // cols >=18 discarded

    // ---- stage ptileB: pf 3ch as bf16x3 in 8 B/px (zero-filled OOB) ----
    for (int p = tid; p < PT * PT; p += 256) {
        const int row = p / PT;
        const int col = p - row * PT;
        const int gy = oy + row, gx = ox + col;
        const bool v = ((unsigned)gy < (unsigned)Hn) && ((unsigned)gx < (unsigned)Wn);
        const size_t gidx = (size_t)b * 3 * HWn + gy * Wn + gx;
        const float v0 = v ? pf[gidx] : 0.f;
        const float v1 = v ? pf[gidx + HWn] : 0.f;
        const float v2 = v ? pf[gidx + 2 * HWn] : 0.f;
        u32x2 q;
        q.x = (unsigned)rne_bf16(v0) | ((unsigned)rne_bf16(v1) << 16);
        q.y = (unsigned)rne_bf16(v2);
        *(u32x2*)(ptileB + p * 2) = q;
    }
    // ---- stage t8b: 8ch conv tile (halo 1), bf16-packed [pix][8ch] ----
    for (int p = tid; p < 324; p += 256) {
        const int row = p / 18;
        const int col = p - row * 18;
        const int gy = tileY0 + row - 1, gx = tileX0 + col - 1;
        const bool v = ((unsigned)gy < (unsigned)Hn) && ((unsigned)gx < (unsigned)Wn);
        const size_t base = (size_t)b * 3 * HWn + gy * Wn + gx;
        float c0 = v ? pf[base] : 0.f;
        float c1 = v ? pf[base + HWn] : 0.f;
        float c2 = v ? pf[base + 2 * HWn] : 0.f;
        float c3 = v ? cf[base] : 0.f;
        float c4 = v ? cf[base + HWn] : 0.f;
        float c5 = v ? cf[base + 2 * HWn] : 0.f;
        const size_t mbase = (size_t)b * 2 * HWn + gy * Wn + gx;
        float c6 = v ? mv[mbase] : 0.f;
        float c7 = v ? mv[mbase + HWn] : 0.f;
        union { unsigned u[4]; f32x4 f; } P;
        P.u[0] = (unsigned)rne_bf16(c0) | ((unsigned)rne_bf16(c1) << 16);
        P.u[1] = (unsigned)rne_bf16(c2) | ((unsigned)rne_bf16(c3) << 16);
        P.u[2] = (unsigned)rne_bf16(c4) | ((unsigned)rne_bf16(c5) << 16);
        P.u[3] = (unsigned)rne_bf16(c6) | ((unsigned)rne_bf16(c7) << 16);
        *(f32x4*)(t8b + p * 4) = P.f;
    }
    __syncthreads();

    // ---- MFMA GEMM [256 x 96] @ [96 x 32], C = bias ----
    f32x4 acc[4][2];
#pragma unroll
    for (int mt = 0; mt < 4; ++mt) {
        acc[mt][0] = (f32x4){bias0, bias0, bias0, bias0};
        acc[mt][1] = (f32x4){bias1, bias1, bias1, bias1};
    }

#pragma unroll
    for (int mt = 0; mt < 4; ++mt) {
        const int mrow = wv * 4 + mt;              // pixel row (ty)
#pragma unroll
        for (int s = 0; s < 3; ++s) {
            const int tap = 4 * s + g;             // this lane's tap
            const int tc  = tap < 9 ? tap : 8;     // pad taps: B=0, any A ok
            const int dy = tc / 3, dx = tc - dy * 3;
            union { f32x4 f; s16x8 v; } A;
            A.f = *(const f32x4*)(t8b + ((mrow + dy) * 18 + (am + dx)) * 4);
            acc[mt][0] = __builtin_amdgcn_mfma_f32_16x16x32_bf16(A.v, bfrag[s][0], acc[mt][0], 0, 0, 0);
            acc[mt][1] = __builtin_amdgcn_mfma_f32_16x16x32_bf16(A.v, bfrag[s][1], acc[mt][1], 0, 0, 0);
        }
    }
    __syncthreads();   // t8b reads done; region becomes offb

    // ---- redistribute D -> offb[pixel][oc], stride 19 (bias included) ----
    float* offb = smem + OFF_T8;
#pragma unroll
    for (int mt = 0; mt < 4; ++mt) {
        const int prow = wv * 4 + mt;
#pragma unroll
        for (int r = 0; r < 4; ++r) {
            const int pix = prow * 16 + (g * 4 + r);
            offb[pix * 19 + am] = acc[mt][0][r];
            if (am < 2) offb[pix * 19 + 16 + am] = acc[mt][1][r];
        }
    }
    __syncthreads();

    // ---- per-pixel offsets + stage-2 deformable conv ----
    const int tx = tid & 15;
    const int ty = tid >> 4;
    const int x = tileX0 + tx;
    const int y = tileY0 + ty;

    f32x2 offs2[9];
#pragma unroll
    for (int j = 0; j < 9; ++j) {
        offs2[j].x = offb[tid * 19 + 2 * j];
        offs2[j].y = offb[tid * 19 + 2 * j + 1];
    }

    const float* p0 = pf + (size_t)b * 3 * HWn;
    f32x2 accP = splat2(0.f);            // outputs 0,1
    float acc2c = 0.f;                   // output 2
    const float tyf = (float)(ty + PH - 1);
    const float txf = (float)(tx + PH - 1);

#pragma unroll
    for (int k = 0; k < 9; ++k) {
        const int ky = k / 3;
        const int kx = k - ky * 3;
        f32x2 basek;
        basek.x = tyf + (float)ky;
        basek.y = txf + (float)kx;
        const f32x2 pyx = offs2[k] + basek;          // tile-relative (y,x)
        const f32x2 fl = vfloor2(pyx);
        const f32x2 w  = pyx - fl;                   // (wy, wx)
        const int ty0 = (int)fl.x;
        const int tx0 = (int)fl.y;
        const float wy = w.x, wx = w.y;

        const bool inT = ((unsigned)ty0 < (unsigned)(PT - 1)) &&
                         ((unsigned)tx0 < (unsigned)(PT - 1));
        float s0, s1, s2;
        if (inT) {
            const int pix = ty0 * PT + tx0;
            const u32x2 r00 = *(const u32x2*)(ptileB + pix * 2);
            const u32x2 r01 = *(const u32x2*)(ptileB + (pix + 1) * 2);
            const u32x2 r10 = *(const u32x2*)(ptileB + (pix + PT) * 2);
            const u32x2 r11 = *(const u32x2*)(ptileB + (pix + PT + 1) * 2);
            // unpack: ch0 = lo<<16, ch1 = lo&0xffff0000, ch2 = hi<<16
            f32x2 q00; q00.x = __uint_as_float(r00.x << 16);
                       q00.y = __uint_as_float(r00.x & 0xffff0000u);
            f32x2 q01; q01.x = __uint_as_float(r01.x << 16);
                       q01.y = __uint_as_float(r01.x & 0xffff0000u);
            f32x2 q10; q10.x = __uint_as_float(r10.x << 16);
                       q10.y = __uint_as_float(r10.x & 0xffff0000u);
            f32x2 q11; q11.x = __uint_as_float(r11.x << 16);
                       q11.y = __uint_as_float(r11.x & 0xffff0000u);
            const float a2 = __uint_as_float(r00.y << 16);
            const float b2 = __uint_as_float(r01.y << 16);
            const float c2 = __uint_as_float(r10.y << 16);
            const float d2 = __uint_as_float(r11.y << 16);
            const f32x2 wx2 = splat2(wx);
            const f32x2 wy2 = splat2(wy);
            const f32x2 h0 = vfma2(wx2, q01 - q00, q00);
            const f32x2 h1 = vfma2(wx2, q11 - q10, q10);
            const f32x2 s01 = vfma2(wy2, h1 - h0, h0);
            const float h0c = fmaf(wx, b2 - a2, a2);
            const float h1c = fmaf(wx, d2 - c2, c2);
            s0 = s01.x; s1 = s01.y;
            s2 = fmaf(wy, h1c - h0c, h0c);
        } else {
            const int y0 = ty0 + oy, x0 = tx0 + ox;
            const int y1 = y0 + 1,  x1 = x0 + 1;
            const bool vy0 = ((unsigned)y0 < (unsigned)Hn);
            const bool vy1 = ((unsigned)y1 < (unsigned)Hn);
            const bool vx0 = ((unsigned)x0 < (unsigned)Wn);
            const bool vx1 = ((unsigned)x1 < (unsigned)Wn);
            const int y0c = min(max(y0, 0), Hn - 1);
            const int y1c = min(max(y1, 0), Hn - 1);
            const int x0c = min(max(x0, 0), Wn - 1);
            const int x1c = min(max(x1, 0), Wn - 1);
            const int i00 = y0c * Wn + x0c;
            const int i01 = y0c * Wn + x1c;
            const int i10 = y1c * Wn + x0c;
            const int i11 = y1c * Wn + x1c;
            const float w00 = (1.f - wy) * (1.f - wx);
            const float w01 = (1.f - wy) * wx;
            const float w10 = wy * (1.f - wx);
            const float w11 = wy * wx;
            float sv[3];
#pragma unroll
            for (int i = 0; i < 3; ++i) {
                const float* pl = p0 + (size_t)i * HWn;
                const float v00 = (vy0 && vx0) ? pl[i00] : 0.f;
                const float v01 = (vy0 && vx1) ? pl[i01] : 0.f;
                const float v10 = (vy1 && vx0) ? pl[i10] : 0.f;
                const float v11 = (vy1 && vx1) ? pl[i11] : 0.f;
                sv[i] = w00 * v00 + w01 * v01 + w10 * v10 + w11 * v11;
            }
            s0 = sv[0]; s1 = sv[1]; s2 = sv[2];
        }
        // epilogue: acc[o] += dw[o][i][k] * s_i  (o pair packed, o=2 scalar)
        {
            f32x2 dwp0; dwp0.x = dw[0 * 27 + 0 * 9 + k]; dwp0.y = dw[1 * 27 + 0 * 9 + k];
            f32x2 dwp1; dwp1.x = dw[0 * 27 + 1 * 9 + k]; dwp1.y = dw[1 * 27 + 1 * 9 + k];
            f32x2 dwp2; dwp2.x = dw[0 * 27 + 2 * 9 + k]; dwp2.y = dw[1 * 27 + 2 * 9 + k];
            accP = vfma2(dwp0, splat2(s0), accP);
            accP = vfma2(dwp1, splat2(s1), accP);
            accP = vfma2(dwp2, splat2(s2), accP);
            acc2c = fmaf(dw[2 * 27 + 0 * 9 + k], s0, acc2c);
            acc2c = fmaf(dw[2 * 27 + 1 * 9 + k], s1, acc2c);
            acc2c = fmaf(dw[2 * 27 + 2 * 9 + k], s2, acc2c);
        }
    }

    const size_t obase = ((size_t)b * 3 * Hn + y) * Wn + x;
    out[obase] = accP.x;
    out[obase + HWn] = accP.y;
    out[obase + 2 * HWn] = acc2c;
}

extern "C" void kernel_launch(void* const* d_in, const int* in_sizes, int n_in,
                              void* d_out, int out_size, void* d_ws, size_t ws_size,
                              hipStream_t stream) {
    const float* pf = (const float*)d_in[0];
    const float* cf = (const float*)d_in[1];
    const float* mv = (const float*)d_in[2];
    const float* ow = (const float*)d_in[3];
    const float* ob = (const float*)d_in[4];
    const float* dw = (const float*)d_in[5];
    float* out = (float*)d_out;
    unsigned short* bwg = (unsigned short*)d_ws;   // 6*64*8 ushorts = 6 KB

    prep_bw<<<6, 64, 0, stream>>>(ow, bwg);
    dim3 grid(Wn / TILE, Hn / TILE, Bn);   // 24 x 24 x 8
    guided_cnn_fused<<<grid, 256, 0, stream>>>(pf, cf, mv, (const s16x8*)bwg, ob, dw, out);
}

// Round 12
// 115.380 us; speedup vs baseline: 1.0158x; 1.0158x over previous
//
#include <hip/hip_runtime.h>

// GuidedCnn: fused offset-conv (8ch -> 18ch, 3x3) + deformable conv.
// R12: 512-thread blocks, 32x16 tile. Halves per-block fixed cost + halo
// redundancy; LDS 46.6 KB -> 3 blocks/CU = 24 waves/CU (75% occ target;
// R11 measured 50% with 256-thr blocks). Keeps: bf16x3-in-8B sampling tile
// (ds_read_b64 corners), pk-fma lerp, bias in MFMA C, B-frags in d_ws,
// K=96 tap-major MFMA GEMM.

#define Bn 8
#define Hn 384
#define Wn 384
#define HWn (Hn * Wn)
#define TW 32                  // tile width
#define TH 16                  // tile height
#define PH 4
#define PTY 24                 // sampling tile rows  (TH + 2*PH)
#define PTX 40                 // sampling tile cols  (TW + 2*PH)
#define CR 18                  // conv tile rows (TH + 2)
#define CC 34                  // conv tile cols (TW + 2)

// LDS float-offset map
#define OFF_PTILE 0
#define SZ_PTILE (PTY * PTX * 2)         // 1920 words: 8 B/px bf16x3
#define OFF_T8   SZ_PTILE
#define SZ_T8U   (512 * 19)              // offb 9728 words; t8b (612*4) unioned
#define SMEM_FLOATS (OFF_T8 + SZ_T8U)    // 11648 floats = 46,592 B

typedef float f32x4 __attribute__((ext_vector_type(4)));
typedef float f32x2 __attribute__((ext_vector_type(2)));
typedef unsigned u32x2 __attribute__((ext_vector_type(2)));
typedef short s16x8 __attribute__((ext_vector_type(8)));

static __device__ inline f32x2 vfma2(f32x2 a, f32x2 b, f32x2 c) {
#if __has_builtin(__builtin_elementwise_fma)
    return __builtin_elementwise_fma(a, b, c);
#else
    f32x2 r; r.x = fmaf(a.x, b.x, c.x); r.y = fmaf(a.y, b.y, c.y); return r;
#endif
}
static __device__ inline f32x2 vfloor2(f32x2 a) {
#if __has_builtin(__builtin_elementwise_floor)
    return __builtin_elementwise_floor(a);
#else
    f32x2 r; r.x = floorf(a.x); r.y = floorf(a.y); return r;
#endif
}
static __device__ inline f32x2 splat2(float s) {
    f32x2 r; r.x = s; r.y = s; return r;
}

__device__ inline unsigned short rne_bf16(float f) {
    unsigned u = __float_as_uint(f);
    u += 0x7fffu + ((u >> 16) & 1u);
    return (unsigned short)(u >> 16);
}

// ---- prep: B-fragments, layout [sg = s*2+nt][lane][j=ch], k = tap*8+ch ----
__global__ void prep_bw(const float* __restrict__ ow, unsigned short* __restrict__ bwg) {
    const int idx = blockIdx.x * 64 + threadIdx.x;   // 0..383
    const int sg   = idx >> 6;
    const int lane = idx & 63;
    const int s  = sg >> 1;
    const int nt = sg & 1;
    const int am = lane & 15;
    const int g  = lane >> 4;
    const int oc = nt * 16 + am;
    const int t  = 4 * s + g;                        // tap 0..11
    union { unsigned short h[8]; s16x8 v; } F;
#pragma unroll
    for (int c = 0; c < 8; ++c) {
        float w = 0.f;
        if (t < 9 && oc < 18) w = ow[oc * 72 + c * 9 + t];
        F.h[c] = rne_bf16(w);
    }
    ((s16x8*)bwg)[idx] = F.v;
}

__global__ __launch_bounds__(512, 6) void guided_cnn_fused(
    const float* __restrict__ pf, const float* __restrict__ cf,
    const float* __restrict__ mv, const s16x8* __restrict__ bwg,
    const float* __restrict__ ob, const float* __restrict__ dw,
    float* __restrict__ out)
{
    __shared__ float smem[SMEM_FLOATS];

    const int tid = threadIdx.x;
    const int b = blockIdx.z;
    const int tileY0 = blockIdx.y * TH;
    const int tileX0 = blockIdx.x * TW;
    const int oy = tileY0 - PH;
    const int ox = tileX0 - PH;

    unsigned* ptileB = (unsigned*)(smem + OFF_PTILE); // [pix]{c0|c1<<16, c2}
    float* t8b = smem + OFF_T8;          // bf16 conv tile: [pix][8ch] = 16B

    const int lane = tid & 63;
    const int wv   = tid >> 6;           // 0..7
    const int am   = lane & 15;
    const int g    = lane >> 4;

    // ---- B-fragments: 6 coalesced b128 loads from precomputed d_ws ----
    s16x8 bfrag[3][2];
#pragma unroll
    for (int s = 0; s < 3; ++s)
#pragma unroll
        for (int nt = 0; nt < 2; ++nt)
            bfrag[s][nt] = bwg[(s * 2 + nt) * 64 + lane];

    // bias for this lane's D-columns (C-operand init)
    const float bias0 = ob[am];
    const float bias1 = ob[am < 2 ? 16 + am : 17];   // cols >=18 discarded

    // ---- stage ptileB: pf 3ch as bf16x3 in 8 B/px (zero-filled OOB) ----
    for (int p = tid; p < PTY * PTX; p += 512) {
        const int row = p / PTX;
        const int col = p - row * PTX;
        const int gy = oy + row, gx = ox + col;
        const bool v = ((unsigned)gy < (unsigned)Hn) && ((unsigned)gx < (unsigned)Wn);
        const size_t gidx = (size_t)b * 3 * HWn + gy * Wn + gx;
        const float v0 = v ? pf[gidx] : 0.f;
        const float v1 = v ? pf[gidx + HWn] : 0.f;
        const float v2 = v ? pf[gidx + 2 * HWn] : 0.f;
        u32x2 q;
        q.x = (unsigned)rne_bf16(v0) | ((unsigned)rne_bf16(v1) << 16);
        q.y = (unsigned)rne_bf16(v2);
        *(u32x2*)(ptileB + p * 2) = q;
    }
    // ---- stage t8b: 8ch conv tile (halo 1), bf16-packed [pix][8ch] ----
    for (int p = tid; p < CR * CC; p += 512) {
        const int row = p / CC;
        const int col = p - row * CC;
        const int gy = tileY0 + row - 1, gx = tileX0 + col - 1;
        const bool v = ((unsigned)gy < (unsigned)Hn) && ((unsigned)gx < (unsigned)Wn);
        const size_t base = (size_t)b * 3 * HWn + gy * Wn + gx;
        float c0 = v ? pf[base] : 0.f;
        float c1 = v ? pf[base + HWn] : 0.f;
        float c2 = v ? pf[base + 2 * HWn] : 0.f;
        float c3 = v ? cf[base] : 0.f;
        float c4 = v ? cf[base + HWn] : 0.f;
        float c5 = v ? cf[base + 2 * HWn] : 0.f;
        const size_t mbase = (size_t)b * 2 * HWn + gy * Wn + gx;
        float c6 = v ? mv[mbase] : 0.f;
        float c7 = v ? mv[mbase + HWn] : 0.f;
        union { unsigned u[4]; f32x4 f; } P;
        P.u[0] = (unsigned)rne_bf16(c0) | ((unsigned)rne_bf16(c1) << 16);
        P.u[1] = (unsigned)rne_bf16(c2) | ((unsigned)rne_bf16(c3) << 16);
        P.u[2] = (unsigned)rne_bf16(c4) | ((unsigned)rne_bf16(c5) << 16);
        P.u[3] = (unsigned)rne_bf16(c6) | ((unsigned)rne_bf16(c7) << 16);
        *(f32x4*)(t8b + p * 4) = P.f;
    }
    __syncthreads();

    // ---- MFMA GEMM [512 x 96] @ [96 x 32], C = bias ----
    // m-tile mt = (ty<<1)|(tx>>4): pixel p_m = mt*16 + (tx&15) = ty*32+tx.
    f32x4 acc[4][2];
#pragma unroll
    for (int mtl = 0; mtl < 4; ++mtl) {
        acc[mtl][0] = (f32x4){bias0, bias0, bias0, bias0};
        acc[mtl][1] = (f32x4){bias1, bias1, bias1, bias1};
    }

#pragma unroll
    for (int mtl = 0; mtl < 4; ++mtl) {
        const int mt = wv * 4 + mtl;               // 0..31
        const int ty = mt >> 1;                    // pixel row 0..15
        const int xh = mt & 1;                     // col half
#pragma unroll
        for (int s = 0; s < 3; ++s) {
            const int tap = 4 * s + g;             // this lane's tap
            const int tc  = tap < 9 ? tap : 8;     // pad taps: B=0, any A ok
            const int dy = tc / 3, dx = tc - dy * 3;
            union { f32x4 f; s16x8 v; } A;
            A.f = *(const f32x4*)(t8b + ((ty + dy) * CC + (xh * 16 + am + dx)) * 4);
            acc[mtl][0] = __builtin_amdgcn_mfma_f32_16x16x32_bf16(A.v, bfrag[s][0], acc[mtl][0], 0, 0, 0);
            acc[mtl][1] = __builtin_amdgcn_mfma_f32_16x16x32_bf16(A.v, bfrag[s][1], acc[mtl][1], 0, 0, 0);
        }
    }
    __syncthreads();   // t8b reads done; region becomes offb

    // ---- redistribute D -> offb[pixel][oc], stride 19 (bias included) ----
    float* offb = smem + OFF_T8;
#pragma unroll
    for (int mtl = 0; mtl < 4; ++mtl) {
        const int mt = wv * 4 + mtl;
#pragma unroll
        for (int r = 0; r < 4; ++r) {
            const int pix = mt * 16 + (g * 4 + r);
            offb[pix * 19 + am] = acc[mtl][0][r];
            if (am < 2) offb[pix * 19 + 16 + am] = acc[mtl][1][r];
        }
    }
    __syncthreads();

    // ---- per-pixel offsets + stage-2 deformable conv (1 px/thread) ----
    const int tx = tid & (TW - 1);
    const int ty = tid >> 5;
    const int x = tileX0 + tx;
    const int y = tileY0 + ty;

    f32x2 offs2[9];
#pragma unroll
    for (int j = 0; j < 9; ++j) {
        offs2[j].x = offb[tid * 19 + 2 * j];
        offs2[j].y = offb[tid * 19 + 2 * j + 1];
    }

    const float* p0 = pf + (size_t)b * 3 * HWn;
    f32x2 accP = splat2(0.f);            // outputs 0,1
    float acc2c = 0.f;                   // output 2
    const float tyf = (float)(ty + PH - 1);
    const float txf = (float)(tx + PH - 1);

#pragma unroll
    for (int k = 0; k < 9; ++k) {
        const int ky = k / 3;
        const int kx = k - ky * 3;
        f32x2 basek;
        basek.x = tyf + (float)ky;
        basek.y = txf + (float)kx;
        const f32x2 pyx = offs2[k] + basek;          // tile-relative (y,x)
        const f32x2 fl = vfloor2(pyx);
        const f32x2 w  = pyx - fl;                   // (wy, wx)
        const int ty0 = (int)fl.x;
        const int tx0 = (int)fl.y;
        const float wy = w.x, wx = w.y;

        const bool inT = ((unsigned)ty0 < (unsigned)(PTY - 1)) &&
                         ((unsigned)tx0 < (unsigned)(PTX - 1));
        float s0, s1, s2;
        if (inT) {
            const int pix = ty0 * PTX + tx0;
            const u32x2 r00 = *(const u32x2*)(ptileB + pix * 2);
            const u32x2 r01 = *(const u32x2*)(ptileB + (pix + 1) * 2);
            const u32x2 r10 = *(const u32x2*)(ptileB + (pix + PTX) * 2);
            const u32x2 r11 = *(const u32x2*)(ptileB + (pix + PTX + 1) * 2);
            f32x2 q00; q00.x = __uint_as_float(r00.x << 16);
                       q00.y = __uint_as_float(r00.x & 0xffff0000u);
            f32x2 q01; q01.x = __uint_as_float(r01.x << 16);
                       q01.y = __uint_as_float(r01.x & 0xffff0000u);
            f32x2 q10; q10.x = __uint_as_float(r10.x << 16);
                       q10.y = __uint_as_float(r10.x & 0xffff0000u);
            f32x2 q11; q11.x = __uint_as_float(r11.x << 16);
                       q11.y = __uint_as_float(r11.x & 0xffff0000u);
            const float a2 = __uint_as_float(r00.y << 16);
            const float b2 = __uint_as_float(r01.y << 16);
            const float c2 = __uint_as_float(r10.y << 16);
            const float d2 = __uint_as_float(r11.y << 16);
            const f32x2 wx2 = splat2(wx);
            const f32x2 wy2 = splat2(wy);
            const f32x2 h0 = vfma2(wx2, q01 - q00, q00);
            const f32x2 h1 = vfma2(wx2, q11 - q10, q10);
            const f32x2 s01 = vfma2(wy2, h1 - h0, h0);
            const float h0c = fmaf(wx, b2 - a2, a2);
            const float h1c = fmaf(wx, d2 - c2, c2);
            s0 = s01.x; s1 = s01.y;
            s2 = fmaf(wy, h1c - h0c, h0c);
        } else {
            const int y0 = ty0 + oy, x0 = tx0 + ox;
            const int y1 = y0 + 1,  x1 = x0 + 1;
            const bool vy0 = ((unsigned)y0 < (unsigned)Hn);
            const bool vy1 = ((unsigned)y1 < (unsigned)Hn);
            const bool vx0 = ((unsigned)x0 < (unsigned)Wn);
            const bool vx1 = ((unsigned)x1 < (unsigned)Wn);
            const int y0c = min(max(y0, 0), Hn - 1);
            const int y1c = min(max(y1, 0), Hn - 1);
            const int x0c = min(max(x0, 0), Wn - 1);
            const int x1c = min(max(x1, 0), Wn - 1);
            const int i00 = y0c * Wn + x0c;
            const int i01 = y0c * Wn + x1c;
            const int i10 = y1c * Wn + x0c;
            const int i11 = y1c * Wn + x1c;
            const float w00 = (1.f - wy) * (1.f - wx);
            const float w01 = (1.f - wy) * wx;
            const float w10 = wy * (1.f - wx);
            const float w11 = wy * wx;
            float sv[3];
#pragma unroll
            for (int i = 0; i < 3; ++i) {
                const float* pl = p0 + (size_t)i * HWn;
                const float v00 = (vy0 && vx0) ? pl[i00] : 0.f;
                const float v01 = (vy0 && vx1) ? pl[i01] : 0.f;
                const float v10 = (vy1 && vx0) ? pl[i10] : 0.f;
                const float v11 = (vy1 && vx1) ? pl[i11] : 0.f;
                sv[i] = w00 * v00 + w01 * v01 + w10 * v10 + w11 * v11;
            }
            s0 = sv[0]; s1 = sv[1]; s2 = sv[2];
        }
        // epilogue: acc[o] += dw[o][i][k] * s_i  (o pair packed, o=2 scalar)
        {
            f32x2 dwp0; dwp0.x = dw[0 * 27 + 0 * 9 + k]; dwp0.y = dw[1 * 27 + 0 * 9 + k];
            f32x2 dwp1; dwp1.x = dw[0 * 27 + 1 * 9 + k]; dwp1.y = dw[1 * 27 + 1 * 9 + k];
            f32x2 dwp2; dwp2.x = dw[0 * 27 + 2 * 9 + k]; dwp2.y = dw[1 * 27 + 2 * 9 + k];
            accP = vfma2(dwp0, splat2(s0), accP);
            accP = vfma2(dwp1, splat2(s1), accP);
            accP = vfma2(dwp2, splat2(s2), accP);
            acc2c = fmaf(dw[2 * 27 + 0 * 9 + k], s0, acc2c);
            acc2c = fmaf(dw[2 * 27 + 1 * 9 + k], s1, acc2c);
            acc2c = fmaf(dw[2 * 27 + 2 * 9 + k], s2, acc2c);
        }
    }

    const size_t obase = ((size_t)b * 3 * Hn + y) * Wn + x;
    out[obase] = accP.x;
    out[obase + HWn] = accP.y;
    out[obase + 2 * HWn] = acc2c;
}

extern "C" void kernel_launch(void* const* d_in, const int* in_sizes, int n_in,
                              void* d_out, int out_size, void* d_ws, size_t ws_size,
                              hipStream_t stream) {
    const float* pf = (const float*)d_in[0];
    const float* cf = (const float*)d_in[1];
    const float* mv = (const float*)d_in[2];
    const float* ow = (const float*)d_in[3];
    const float* ob = (const float*)d_in[4];
    const float* dw = (const float*)d_in[5];
    float* out = (float*)d_out;
    unsigned short* bwg = (unsigned short*)d_ws;   // 6*64*8 ushorts = 6 KB

    prep_bw<<<6, 64, 0, stream>>>(ow, bwg);
    dim3 grid(Wn / TW, Hn / TH, Bn);   // 12 x 24 x 8 = 2304
    guided_cnn_fused<<<grid, 512, 0, stream>>>(pf, cf, mv, (const s16x8*)bwg, ob, dw, out);
}